// Round 9
// baseline (128.644 us; speedup 1.0000x reference)
//
#include <hip/hip_runtime.h>
#include <stdint.h>

constexpr int N_PTS = 8192;
constexpr int S_CTR = 2048;
constexpr int BATCH = 4;
constexpr int CHANS = 64;
constexpr int KS = 32;
constexpr int CH_OUT = CHANS + 3;   // 67
constexpr int GD = 10;              // grid cells per dim (cell = radius = 0.1)
constexpr int NCELL = GD * GD * GD; // 1000
constexpr int CAP = 128;            // max candidates per center (mean ~34, ~16 sigma)

// Exact cell index: f32 -> f64 mul by 10 is exact, so floor has no rounding
// window; +-1 neighbor range provably covers every r=0.1 ball.
__device__ __forceinline__ int cell_of(float p) {
    int c = (int)((double)p * 10.0);
    return c < 0 ? 0 : (c > GD - 1 ? GD - 1 : c);
}

// q[l>>2] element (l&3), l compile-time constant after unroll
#define Q_EL(l) (((l) & 3) == 0 ? q[(l) >> 2].x : ((l) & 3) == 1 ? q[(l) >> 2].y \
               : ((l) & 3) == 2 ? q[(l) >> 2].z : q[(l) >> 2].w)

// ---------------- K1: blocks 0-3: hist+scan+scatter  ||  rest: transpose ----
// The hist/scan/scatter for batch b runs entirely in one block (LDS offsets,
// LDS-atomic slot grab), concurrent with the 512 transpose blocks.
__global__ __launch_bounds__(256) void build_transpose(
    const float* __restrict__ xyz, const float* __restrict__ feat,
    int* __restrict__ cellStart, float4* __restrict__ sPts,
    float* __restrict__ featT)
{
    if (blockIdx.x < (unsigned)BATCH) {
        __shared__ int cnts[1024];              // 1000 cells, padded
        __shared__ int part[256];
        const int b = blockIdx.x, t = threadIdx.x;
        cnts[t] = 0; cnts[t + 256] = 0; cnts[t + 512] = 0; cnts[t + 768] = 0;
        __syncthreads();
        const float* xb = xyz + (size_t)b * N_PTS * 3;
        // ---- histogram (LDS atomics)
        for (int j = 0; j < 32; ++j) {
            const int i = t + j * 256;          // coalesced 12B/lane
            const float x = xb[i * 3], y = xb[i * 3 + 1], z = xb[i * 3 + 2];
            atomicAdd(&cnts[(cell_of(z) * GD + cell_of(y)) * GD + cell_of(x)], 1);
        }
        __syncthreads();
        // ---- scan (4 cells/thread + Hillis-Steele over partials)
        const int c0 = cnts[4 * t], c1 = cnts[4 * t + 1],
                  c2 = cnts[4 * t + 2], c3 = cnts[4 * t + 3];
        part[t] = c0 + c1 + c2 + c3;
        __syncthreads();
        for (int o = 1; o < 256; o <<= 1) {
            const int v = (t >= o) ? part[t - o] : 0;
            __syncthreads();
            part[t] += v;
            __syncthreads();
        }
        const int base = (t == 0) ? 0 : part[t - 1];
        const int e0 = base, e1 = base + c0, e2 = e1 + c1, e3 = e2 + c2;
        const int cb = b * (NCELL + 1);
        if (4 * t + 0 < NCELL) cellStart[cb + 4 * t + 0] = e0;
        if (4 * t + 1 < NCELL) cellStart[cb + 4 * t + 1] = e1;
        if (4 * t + 2 < NCELL) cellStart[cb + 4 * t + 2] = e2;
        if (4 * t + 3 < NCELL) cellStart[cb + 4 * t + 3] = e3;
        if (t == 0) cellStart[cb + NCELL] = N_PTS;
        // overwrite cnts with running offsets (each thread owns its 4 slots)
        cnts[4 * t] = e0; cnts[4 * t + 1] = e1;
        cnts[4 * t + 2] = e2; cnts[4 * t + 3] = e3;
        __syncthreads();
        // ---- scatter into cell-sorted float4 SoA (LDS-atomic slot grab)
        for (int j = 0; j < 32; ++j) {
            const int i = t + j * 256;
            const float x = xb[i * 3], y = xb[i * 3 + 1], z = xb[i * 3 + 2];
            const int c = (cell_of(z) * GD + cell_of(y)) * GD + cell_of(x);
            const int pos = atomicAdd(&cnts[c], 1);
            sPts[b * N_PTS + pos] = make_float4(x, y, z, __int_as_float(i));
        }
    } else {
        // ---- transpose (B,C,N)->(B,N,C), float4 both sides, 64x64 tile
        __shared__ float tile[64][65];          // <=2-way LDS conflicts (free)
        const int bx = blockIdx.x - BATCH;      // 0..511
        const int t = threadIdx.x;
        const int n0 = (bx & 127) * 64;
        const int b = bx >> 7;
        const float* fb = feat + (size_t)b * CHANS * N_PTS;
#pragma unroll
        for (int r = 0; r < 4; ++r) {
            const int c = (t >> 4) + 16 * r;
            const float4 v =
                *(const float4*)(fb + (size_t)c * N_PTS + n0 + (t & 15) * 4);
            tile[c][(t & 15) * 4 + 0] = v.x;
            tile[c][(t & 15) * 4 + 1] = v.y;
            tile[c][(t & 15) * 4 + 2] = v.z;
            tile[c][(t & 15) * 4 + 3] = v.w;
        }
        __syncthreads();
        float* ob = featT + ((size_t)b * N_PTS + n0) * CHANS;
#pragma unroll
        for (int r = 0; r < 4; ++r) {
            const int n = (t >> 4) + 16 * r;
            const int c = (t & 15) * 4;
            const float4 v = make_float4(tile[c][n], tile[c + 1][n],
                                         tile[c + 2][n], tile[c + 3][n]);
            *(float4*)(ob + (size_t)n * CHANS + c) = v;
        }
    }
}

// ---------------- K2: fused ball-query + gather (one wave per center) -------
// Query: collect ALL in-ball original ids (grid order), bitonic-sort 128
// (2 regs/lane), first 32 == sort(where(in_ball, arange, N))[:32].
// Gather: same wave broadcasts ids via shfl; half 0 writes ch 0-33,
// half 1 writes ch 34-66. All featT refs are compile-time register indices.
__global__ __launch_bounds__(256) void bq_gather(
    const float* __restrict__ xyz, const float* __restrict__ ctr,
    const int* __restrict__ cellStart, const float4* __restrict__ sPts,
    const float* __restrict__ featT, float* __restrict__ out)
{
    __shared__ int cand[4][CAP];
    const int wave = threadIdx.x >> 6, lane = threadIdx.x & 63;
    const int cg = blockIdx.x * 4 + wave;       // center id 0..B*S-1
    const int b = cg >> 11;
    const int s = cg & (S_CTR - 1);
    const float cx = ctr[(size_t)cg * 3];
    const float cy = ctr[(size_t)cg * 3 + 1];
    const float cz = ctr[(size_t)cg * 3 + 2];
    const float r2 = (float)(0.1 * 0.1);        // bit-exact f64->f32 threshold

    const int ix = cell_of(cx), iy = cell_of(cy), iz = cell_of(cz);
    const int xlo = max(ix - 1, 0), xhi = min(ix + 1, GD - 1);
    const int ylo = max(iy - 1, 0), yhi = min(iy + 1, GD - 1);
    const int zlo = max(iz - 1, 0), zhi = min(iz + 1, GD - 1);

    unsigned cnt = 0;
    const int csb = b * (NCELL + 1);
    const int pb = b * N_PTS;

    for (int zz = zlo; zz <= zhi; ++zz)
        for (int yy = ylo; yy <= yhi; ++yy) {
            const int rowc = (zz * GD + yy) * GD;
            const int rs = cellStart[csb + rowc + xlo];
            const int re = cellStart[csb + rowc + xhi + 1];
            for (int p0 = rs; p0 < re; p0 += 64) {
                const int i = p0 + lane;
                const bool valid = i < re;
                float px = 1e9f, py = 1e9f, pz = 1e9f; int oid = 0;
                if (valid) {
                    const float4 v = sPts[pb + i];   // one 16B coalesced load
                    px = v.x; py = v.y; pz = v.z; oid = __float_as_int(v.w);
                }
                // exact non-fused f32, XLA order: (dx^2 + dy^2) + dz^2
                const float dx = __fsub_rn(cx, px);
                const float dy = __fsub_rn(cy, py);
                const float dz = __fsub_rn(cz, pz);
                const float d2 = __fadd_rn(
                    __fadd_rn(__fmul_rn(dx, dx), __fmul_rn(dy, dy)),
                    __fmul_rn(dz, dz));
                const bool inb = valid && (d2 < r2);
                const unsigned long long mask = __ballot(inb);
                if (mask) {                         // wave-uniform
                    const unsigned rank = __builtin_amdgcn_mbcnt_hi(
                        (unsigned)(mask >> 32),
                        __builtin_amdgcn_mbcnt_lo((unsigned)mask, 0u));
                    if (inb) {
                        const unsigned slot = cnt + rank;
                        if (slot < (unsigned)CAP) cand[wave][slot] = oid;
                    }
                    cnt += (unsigned)__popcll(mask);
                }
            }
        }
    if (cnt > (unsigned)CAP) cnt = CAP;

    // bitonic sort of 128 (v0 at pos lane, v1 at pos lane+64), ascending
    int v0 = (lane < (int)cnt) ? cand[wave][lane] : 0x7fffffff;
    int v1 = (lane + 64 < (int)cnt) ? cand[wave][lane + 64] : 0x7fffffff;
#pragma unroll
    for (int k = 2; k <= 128; k <<= 1) {
        if (k == 128) {                    // j=64 stage: cross-reg, ascending
            const int a = min(v0, v1); v1 = max(v0, v1); v0 = a;
        }
#pragma unroll
        for (int j = (k == 128 ? 32 : (k >> 1)); j >= 1; j >>= 1) {
            const int o0 = __shfl_xor(v0, j);
            const int o1 = __shfl_xor(v1, j);
            const bool lower = (lane & j) == 0;
            bool up0, up1;
            if (k == 64)       { up0 = true;  up1 = false; }
            else if (k == 128) { up0 = true;  up1 = true;  }
            else { const bool u = (lane & k) == 0; up0 = u; up1 = u; }
            v0 = (up0 == lower) ? min(v0, o0) : max(v0, o0);
            v1 = (up1 == lower) ? min(v1, o1) : max(v1, o1);
        }
    }

    int first = __shfl(v0, 0);
    if (cnt == 0u) first = 0;
    const int k = lane & 31;
    const int v0k = __shfl(v0, k);               // both halves get slot k's id
    const int id = (k < (int)cnt) ? v0k : first;

    // ---- gather phase ----
    const float* pp = xyz + ((size_t)b * N_PTS + id) * 3;
    const float g0 = __fsub_rn(pp[0], cx);
    const float g1 = __fsub_rn(pp[1], cy);
    const float g2 = __fsub_rn(pp[2], cz);

    const int h = lane >> 5;                     // half: 0 -> ch 0-33, 1 -> ch 34-66
    const size_t chs = (size_t)S_CTR * KS;
    float* ob = out + ((size_t)b * CH_OUT * S_CTR + s) * KS + k;
    float* obh = ob + (size_t)(34 * h) * chs;

    // q[j] = feat[28h + 4j .. 28h + 4j + 3] for this id
    const float4* fq =
        (const float4*)(featT + ((size_t)b * N_PTS + id) * CHANS) + 7 * h;
    float4 q[9];
#pragma unroll
    for (int j = 0; j < 9; ++j) q[j] = fq[j];

    // i=0..2: h0 -> grouped xyz; h1 -> feat 31,32,33 (locals 3,4,5)
    __builtin_nontemporal_store(h ? q[0].w : g0, obh);
    __builtin_nontemporal_store(h ? q[1].x : g1, obh + chs);
    __builtin_nontemporal_store(h ? q[1].y : g2, obh + 2 * chs);
#pragma unroll
    for (int i = 3; i <= 32; ++i) {              // h0: feat i-3 ; h1: feat 31+i
        const float d = h ? Q_EL(i + 3) : Q_EL(i - 3);
        __builtin_nontemporal_store(d, obh + (size_t)i * chs);
    }
    if (!h)                                      // ch 33 = feat 30 (h0 only)
        __builtin_nontemporal_store(Q_EL(30), obh + (size_t)33 * chs);
}

// ---------------- Fallback: brute-force bq + direct gather ------------------
__global__ __launch_bounds__(256) void bq_brute(
    const float* __restrict__ xyz, const float* __restrict__ ctr,
    int* __restrict__ idx_out)
{
    const int wave = threadIdx.x >> 6, lane = threadIdx.x & 63;
    const int cg = blockIdx.x * 4 + wave;
    const int b = cg >> 11;
    const float* xb = xyz + (size_t)b * N_PTS * 3;
    const float cx = ctr[(size_t)cg * 3], cy = ctr[(size_t)cg * 3 + 1],
                cz = ctr[(size_t)cg * 3 + 2];
    __shared__ int lidx[4][KS];
    unsigned cnt = 0;
    const float r2 = (float)(0.1 * 0.1);
    for (int n0 = 0; n0 < N_PTS && cnt < (unsigned)KS; n0 += 64) {
        const int n = n0 + lane;
        const float px = xb[n * 3], py = xb[n * 3 + 1], pz = xb[n * 3 + 2];
        const float dx = __fsub_rn(cx, px), dy = __fsub_rn(cy, py),
                    dz = __fsub_rn(cz, pz);
        const float d2 = __fadd_rn(
            __fadd_rn(__fmul_rn(dx, dx), __fmul_rn(dy, dy)), __fmul_rn(dz, dz));
        const bool inb = d2 < r2;
        const unsigned long long mask = __ballot(inb);
        if (mask) {
            const unsigned rank = __builtin_amdgcn_mbcnt_hi(
                (unsigned)(mask >> 32),
                __builtin_amdgcn_mbcnt_lo((unsigned)mask, 0u));
            const unsigned slot = cnt + rank;
            if (inb && slot < (unsigned)KS) lidx[wave][slot] = n;
            cnt += (unsigned)__popcll(mask);
        }
    }
    if (cnt > (unsigned)KS) cnt = KS;
    const int first = (cnt > 0) ? lidx[wave][0] : 0;
    if (lane < KS)
        idx_out[(size_t)cg * KS + lane] = (lane < (int)cnt) ? lidx[wave][lane] : first;
}

__global__ __launch_bounds__(256) void gather_direct(
    const float* __restrict__ xyz, const float* __restrict__ ctr,
    const float* __restrict__ feat, const int* __restrict__ idx_ws,
    float* __restrict__ out)
{
    const int wave = threadIdx.x >> 6, lane = threadIdx.x & 63;
    const int cg = blockIdx.x * 4 + wave;
    const int b = cg >> 11;
    const int s = cg & (S_CTR - 1);
    const int k = lane & 31;
    const int half = lane >> 5;
    const int id = idx_ws[(size_t)cg * KS + k];
    const float* pp = xyz + ((size_t)b * N_PTS + id) * 3;
    const float* cc = ctr + (size_t)cg * 3;
    const float g0 = __fsub_rn(pp[0], cc[0]);
    const float g1 = __fsub_rn(pp[1], cc[1]);
    const float g2 = __fsub_rn(pp[2], cc[2]);
    const float* fb = feat + (size_t)b * CHANS * N_PTS + id;
    float* ob = out + ((size_t)b * CH_OUT * S_CTR + s) * KS + k;
    const size_t chs = (size_t)S_CTR * KS;
#pragma unroll
    for (int ch0 = 0; ch0 < CH_OUT; ch0 += 2) {
        const int ch = ch0 + half;
        if (ch < CH_OUT) {
            float v;
            if (ch0 == 0)      v = half ? g1 : g0;
            else if (ch0 == 2) v = half ? fb[0] : g2;
            else               v = fb[(size_t)(ch - 3) * N_PTS];
            ob[(size_t)ch * chs] = v;
        }
    }
}

extern "C" void kernel_launch(void* const* d_in, const int* in_sizes, int n_in,
                              void* d_out, int out_size, void* d_ws, size_t ws_size,
                              hipStream_t stream)
{
    const float* xyz  = (const float*)d_in[0];   // (B,N,3) f32
    const float* ctr  = (const float*)d_in[1];   // (B,S,3) f32
    const float* feat = (const float*)d_in[2];   // (B,C,N) f32
    float* out = (float*)d_out;                  // (B,67,S,K) f32

    // workspace layout (16B-aligned)
    char* w = (char*)d_ws;
    const size_t cs_off    = 0;                          // 4*1001*4 = 16016
    const size_t spts_off  = 16384;                      // 4*8192*16 = 512K
    const size_t featT_off = 16384 + 524288;             // 8 MB
    const size_t total_need = featT_off + (size_t)BATCH * N_PTS * CHANS * 4;

    if (ws_size >= total_need) {
        int*    cellStart = (int*)(w + cs_off);
        float4* sPts      = (float4*)(w + spts_off);
        float*  featT     = (float*)(w + featT_off);

        build_transpose<<<dim3(BATCH + BATCH * (N_PTS / 64)), dim3(256),
                          0, stream>>>(xyz, feat, cellStart, sPts, featT);
        bq_gather<<<dim3(BATCH * S_CTR / 4), dim3(256), 0, stream>>>(
            xyz, ctr, cellStart, sPts, featT, out);
    } else {
        int* idx_ws = (int*)w;                   // 1 MB
        bq_brute<<<dim3(BATCH * S_CTR / 4), dim3(256), 0, stream>>>(
            xyz, ctr, idx_ws);
        gather_direct<<<dim3(BATCH * S_CTR / 4), dim3(256), 0, stream>>>(
            xyz, ctr, feat, idx_ws, out);
    }
}

// Round 11
// 116.784 us; speedup vs baseline: 1.1016x; 1.1016x over previous
//
#include <hip/hip_runtime.h>
#include <stdint.h>

constexpr int N_PTS = 8192;
constexpr int S_CTR = 2048;
constexpr int BATCH = 4;
constexpr int CHANS = 64;
constexpr int KS = 32;
constexpr int CH_OUT = CHANS + 3;   // 67
constexpr int GD = 10;              // grid cells per dim (cell = radius = 0.1)
constexpr int NCELL = GD * GD * GD; // 1000
constexpr int CAP = 128;            // max candidates per center (mean ~34, ~16 sigma)

// Exact cell index: f32 -> f64 mul by 10 is exact, so floor has no rounding
// window; +-1 neighbor range provably covers every r=0.1 ball.
__device__ __forceinline__ int cell_of(float p) {
    int c = (int)((double)p * 10.0);
    return c < 0 ? 0 : (c > GD - 1 ? GD - 1 : c);
}

// q[l>>2] element (l&3), l compile-time constant after unroll
#define Q_EL(l) (((l) & 3) == 0 ? q[(l) >> 2].x : ((l) & 3) == 1 ? q[(l) >> 2].y \
               : ((l) & 3) == 2 ? q[(l) >> 2].z : q[(l) >> 2].w)

// ---------------- K1: per-batch hist+scan (blocks 0-3)  ||  transpose -------
// (R8 structure: scatter stays a separate 128-block kernel — putting it in
//  here (R9) serialized 32K scatters onto 4 CUs and cost ~8 us critical path.)
__global__ __launch_bounds__(256) void histscan_transpose(
    const float* __restrict__ xyz, const float* __restrict__ feat,
    int* __restrict__ cellStart, int* __restrict__ gOff,
    float* __restrict__ featT)
{
    if (blockIdx.x < (unsigned)BATCH) {
        // ---- histogram + scan for batch b (LDS atomics, no global zeroing)
        __shared__ int cnts[1024];              // 1000 cells, padded
        __shared__ int part[256];
        const int b = blockIdx.x, t = threadIdx.x;
        cnts[t] = 0; cnts[t + 256] = 0; cnts[t + 512] = 0; cnts[t + 768] = 0;
        __syncthreads();
        const float* xb = xyz + (size_t)b * N_PTS * 3;
        for (int j = 0; j < 32; ++j) {
            const int i = t + j * 256;          // coalesced 12B/lane
            const float x = xb[i * 3], y = xb[i * 3 + 1], z = xb[i * 3 + 2];
            atomicAdd(&cnts[(cell_of(z) * GD + cell_of(y)) * GD + cell_of(x)], 1);
        }
        __syncthreads();
        const int c0 = cnts[4 * t], c1 = cnts[4 * t + 1],
                  c2 = cnts[4 * t + 2], c3 = cnts[4 * t + 3];
        part[t] = c0 + c1 + c2 + c3;
        __syncthreads();
        for (int o = 1; o < 256; o <<= 1) {     // Hillis-Steele inclusive scan
            const int v = (t >= o) ? part[t - o] : 0;
            __syncthreads();
            part[t] += v;
            __syncthreads();
        }
        const int base = (t == 0) ? 0 : part[t - 1];
        const int e0 = base, e1 = base + c0, e2 = e1 + c1, e3 = e2 + c2;
        const int cb = b * (NCELL + 1);
        if (4 * t + 0 < NCELL) { cellStart[cb + 4 * t + 0] = e0; gOff[b * NCELL + 4 * t + 0] = e0; }
        if (4 * t + 1 < NCELL) { cellStart[cb + 4 * t + 1] = e1; gOff[b * NCELL + 4 * t + 1] = e1; }
        if (4 * t + 2 < NCELL) { cellStart[cb + 4 * t + 2] = e2; gOff[b * NCELL + 4 * t + 2] = e2; }
        if (4 * t + 3 < NCELL) { cellStart[cb + 4 * t + 3] = e3; gOff[b * NCELL + 4 * t + 3] = e3; }
        if (t == 0) cellStart[cb + NCELL] = N_PTS;
    } else {
        // ---- transpose (B,C,N)->(B,N,C), float4 both sides, 64x64 tile
        __shared__ float tile[64][65];          // <=2-way LDS conflicts (free)
        const int bx = blockIdx.x - BATCH;      // 0..511
        const int t = threadIdx.x;
        const int n0 = (bx & 127) * 64;
        const int b = bx >> 7;
        const float* fb = feat + (size_t)b * CHANS * N_PTS;
#pragma unroll
        for (int r = 0; r < 4; ++r) {
            const int c = (t >> 4) + 16 * r;
            const float4 v =
                *(const float4*)(fb + (size_t)c * N_PTS + n0 + (t & 15) * 4);
            tile[c][(t & 15) * 4 + 0] = v.x;
            tile[c][(t & 15) * 4 + 1] = v.y;
            tile[c][(t & 15) * 4 + 2] = v.z;
            tile[c][(t & 15) * 4 + 3] = v.w;
        }
        __syncthreads();
        float* ob = featT + ((size_t)b * N_PTS + n0) * CHANS;
#pragma unroll
        for (int r = 0; r < 4; ++r) {
            const int n = (t >> 4) + 16 * r;
            const int c = (t & 15) * 4;
            const float4 v = make_float4(tile[c][n], tile[c + 1][n],
                                         tile[c + 2][n], tile[c + 3][n]);
            *(float4*)(ob + (size_t)n * CHANS + c) = v;
        }
    }
}

// ---------------- K2: scatter into cell-sorted float4 SoA -------------------
__global__ __launch_bounds__(256) void grid_scatter(
    const float* __restrict__ xyz, int* __restrict__ gOff,
    float4* __restrict__ sPts)
{
    const int i = blockIdx.x * 256 + threadIdx.x;   // 0..32767
    const int b = i >> 13;
    const int p = i & (N_PTS - 1);
    const float* xp = xyz + (size_t)b * N_PTS * 3 + (size_t)p * 3;
    const float x = xp[0], y = xp[1], z = xp[2];
    const int c = (cell_of(z) * GD + cell_of(y)) * GD + cell_of(x);
    const int pos = atomicAdd(&gOff[b * NCELL + c], 1);
    sPts[b * N_PTS + pos] = make_float4(x, y, z, __int_as_float(p));
}

// ---------------- K3: fused ball-query + gather (one wave per center) -------
// Query: collect ALL in-ball original ids (grid order), bitonic-sort 128
// (2 regs/lane), first 32 == sort(where(in_ball, arange, N))[:32].
// Gather: same wave broadcasts ids via shfl; half 0 writes ch 0-33,
// half 1 writes ch 34-66. All featT refs are compile-time register indices.
__global__ __launch_bounds__(256) void bq_gather(
    const float* __restrict__ xyz, const float* __restrict__ ctr,
    const int* __restrict__ cellStart, const float4* __restrict__ sPts,
    const float* __restrict__ featT, float* __restrict__ out)
{
    __shared__ int cand[4][CAP];
    const int wave = threadIdx.x >> 6, lane = threadIdx.x & 63;
    const int cg = blockIdx.x * 4 + wave;       // center id 0..B*S-1
    const int b = cg >> 11;
    const int s = cg & (S_CTR - 1);
    const float cx = ctr[(size_t)cg * 3];
    const float cy = ctr[(size_t)cg * 3 + 1];
    const float cz = ctr[(size_t)cg * 3 + 2];
    const float r2 = (float)(0.1 * 0.1);        // bit-exact f64->f32 threshold

    const int ix = cell_of(cx), iy = cell_of(cy), iz = cell_of(cz);
    const int xlo = max(ix - 1, 0), xhi = min(ix + 1, GD - 1);
    const int ylo = max(iy - 1, 0), yhi = min(iy + 1, GD - 1);
    const int zlo = max(iz - 1, 0), zhi = min(iz + 1, GD - 1);

    unsigned cnt = 0;
    const int csb = b * (NCELL + 1);
    const int pb = b * N_PTS;

    for (int zz = zlo; zz <= zhi; ++zz)
        for (int yy = ylo; yy <= yhi; ++yy) {
            const int rowc = (zz * GD + yy) * GD;
            const int rs = cellStart[csb + rowc + xlo];
            const int re = cellStart[csb + rowc + xhi + 1];
            for (int p0 = rs; p0 < re; p0 += 64) {
                const int i = p0 + lane;
                const bool valid = i < re;
                float px = 1e9f, py = 1e9f, pz = 1e9f; int oid = 0;
                if (valid) {
                    const float4 v = sPts[pb + i];   // one 16B coalesced load
                    px = v.x; py = v.y; pz = v.z; oid = __float_as_int(v.w);
                }
                // exact non-fused f32, XLA order: (dx^2 + dy^2) + dz^2
                const float dx = __fsub_rn(cx, px);
                const float dy = __fsub_rn(cy, py);
                const float dz = __fsub_rn(cz, pz);
                const float d2 = __fadd_rn(
                    __fadd_rn(__fmul_rn(dx, dx), __fmul_rn(dy, dy)),
                    __fmul_rn(dz, dz));
                const bool inb = valid && (d2 < r2);
                const unsigned long long mask = __ballot(inb);
                if (mask) {                         // wave-uniform
                    const unsigned rank = __builtin_amdgcn_mbcnt_hi(
                        (unsigned)(mask >> 32),
                        __builtin_amdgcn_mbcnt_lo((unsigned)mask, 0u));
                    if (inb) {
                        const unsigned slot = cnt + rank;
                        if (slot < (unsigned)CAP) cand[wave][slot] = oid;
                    }
                    cnt += (unsigned)__popcll(mask);
                }
            }
        }
    if (cnt > (unsigned)CAP) cnt = CAP;

    // bitonic sort of 128 (v0 at pos lane, v1 at pos lane+64), ascending
    int v0 = (lane < (int)cnt) ? cand[wave][lane] : 0x7fffffff;
    int v1 = (lane + 64 < (int)cnt) ? cand[wave][lane + 64] : 0x7fffffff;
#pragma unroll
    for (int k = 2; k <= 128; k <<= 1) {
        if (k == 128) {                    // j=64 stage: cross-reg, ascending
            const int a = min(v0, v1); v1 = max(v0, v1); v0 = a;
        }
#pragma unroll
        for (int j = (k == 128 ? 32 : (k >> 1)); j >= 1; j >>= 1) {
            const int o0 = __shfl_xor(v0, j);
            const int o1 = __shfl_xor(v1, j);
            const bool lower = (lane & j) == 0;
            bool up0, up1;
            if (k == 64)       { up0 = true;  up1 = false; }
            else if (k == 128) { up0 = true;  up1 = true;  }
            else { const bool u = (lane & k) == 0; up0 = u; up1 = u; }
            v0 = (up0 == lower) ? min(v0, o0) : max(v0, o0);
            v1 = (up1 == lower) ? min(v1, o1) : max(v1, o1);
        }
    }

    int first = __shfl(v0, 0);
    if (cnt == 0u) first = 0;
    const int k = lane & 31;
    const int v0k = __shfl(v0, k);               // both halves get slot k's id
    const int id = (k < (int)cnt) ? v0k : first;

    // ---- gather phase ----
    const float* pp = xyz + ((size_t)b * N_PTS + id) * 3;
    const float g0 = __fsub_rn(pp[0], cx);
    const float g1 = __fsub_rn(pp[1], cy);
    const float g2 = __fsub_rn(pp[2], cz);

    const int h = lane >> 5;                     // half: 0 -> ch 0-33, 1 -> ch 34-66
    const size_t chs = (size_t)S_CTR * KS;
    float* ob = out + ((size_t)b * CH_OUT * S_CTR + s) * KS + k;
    float* obh = ob + (size_t)(34 * h) * chs;

    // q[j] = feat[28h + 4j .. 28h + 4j + 3] for this id
    const float4* fq =
        (const float4*)(featT + ((size_t)b * N_PTS + id) * CHANS) + 7 * h;
    float4 q[9];
#pragma unroll
    for (int j = 0; j < 9; ++j) q[j] = fq[j];

    // i=0..2: h0 -> grouped xyz; h1 -> feat 31,32,33 (locals 3,4,5)
    __builtin_nontemporal_store(h ? q[0].w : g0, obh);
    __builtin_nontemporal_store(h ? q[1].x : g1, obh + chs);
    __builtin_nontemporal_store(h ? q[1].y : g2, obh + 2 * chs);
#pragma unroll
    for (int i = 3; i <= 32; ++i) {              // h0: feat i-3 ; h1: feat 31+i
        const float d = h ? Q_EL(i + 3) : Q_EL(i - 3);
        __builtin_nontemporal_store(d, obh + (size_t)i * chs);
    }
    if (!h)                                      // ch 33 = feat 30 (h0 only)
        __builtin_nontemporal_store(Q_EL(30), obh + (size_t)33 * chs);
}

// ---------------- Fallback: brute-force bq + direct gather ------------------
__global__ __launch_bounds__(256) void bq_brute(
    const float* __restrict__ xyz, const float* __restrict__ ctr,
    int* __restrict__ idx_out)
{
    const int wave = threadIdx.x >> 6, lane = threadIdx.x & 63;
    const int cg = blockIdx.x * 4 + wave;
    const int b = cg >> 11;
    const float* xb = xyz + (size_t)b * N_PTS * 3;
    const float cx = ctr[(size_t)cg * 3], cy = ctr[(size_t)cg * 3 + 1],
                cz = ctr[(size_t)cg * 3 + 2];
    __shared__ int lidx[4][KS];
    unsigned cnt = 0;
    const float r2 = (float)(0.1 * 0.1);
    for (int n0 = 0; n0 < N_PTS && cnt < (unsigned)KS; n0 += 64) {
        const int n = n0 + lane;
        const float px = xb[n * 3], py = xb[n * 3 + 1], pz = xb[n * 3 + 2];
        const float dx = __fsub_rn(cx, px), dy = __fsub_rn(cy, py),
                    dz = __fsub_rn(cz, pz);
        const float d2 = __fadd_rn(
            __fadd_rn(__fmul_rn(dx, dx), __fmul_rn(dy, dy)), __fmul_rn(dz, dz));
        const bool inb = d2 < r2;
        const unsigned long long mask = __ballot(inb);
        if (mask) {
            const unsigned rank = __builtin_amdgcn_mbcnt_hi(
                (unsigned)(mask >> 32),
                __builtin_amdgcn_mbcnt_lo((unsigned)mask, 0u));
            const unsigned slot = cnt + rank;
            if (inb && slot < (unsigned)KS) lidx[wave][slot] = n;
            cnt += (unsigned)__popcll(mask);
        }
    }
    if (cnt > (unsigned)KS) cnt = KS;
    const int first = (cnt > 0) ? lidx[wave][0] : 0;
    if (lane < KS)
        idx_out[(size_t)cg * KS + lane] = (lane < (int)cnt) ? lidx[wave][lane] : first;
}

__global__ __launch_bounds__(256) void gather_direct(
    const float* __restrict__ xyz, const float* __restrict__ ctr,
    const float* __restrict__ feat, const int* __restrict__ idx_ws,
    float* __restrict__ out)
{
    const int wave = threadIdx.x >> 6, lane = threadIdx.x & 63;
    const int cg = blockIdx.x * 4 + wave;
    const int b = cg >> 11;
    const int s = cg & (S_CTR - 1);
    const int k = lane & 31;
    const int half = lane >> 5;
    const int id = idx_ws[(size_t)cg * KS + k];
    const float* pp = xyz + ((size_t)b * N_PTS + id) * 3;
    const float* cc = ctr + (size_t)cg * 3;
    const float g0 = __fsub_rn(pp[0], cc[0]);
    const float g1 = __fsub_rn(pp[1], cc[1]);
    const float g2 = __fsub_rn(pp[2], cc[2]);
    const float* fb = feat + (size_t)b * CHANS * N_PTS + id;
    float* ob = out + ((size_t)b * CH_OUT * S_CTR + s) * KS + k;
    const size_t chs = (size_t)S_CTR * KS;
#pragma unroll
    for (int ch0 = 0; ch0 < CH_OUT; ch0 += 2) {
        const int ch = ch0 + half;
        if (ch < CH_OUT) {
            float v;
            if (ch0 == 0)      v = half ? g1 : g0;
            else if (ch0 == 2) v = half ? fb[0] : g2;
            else               v = fb[(size_t)(ch - 3) * N_PTS];
            ob[(size_t)ch * chs] = v;
        }
    }
}

extern "C" void kernel_launch(void* const* d_in, const int* in_sizes, int n_in,
                              void* d_out, int out_size, void* d_ws, size_t ws_size,
                              hipStream_t stream)
{
    const float* xyz  = (const float*)d_in[0];   // (B,N,3) f32
    const float* ctr  = (const float*)d_in[1];   // (B,S,3) f32
    const float* feat = (const float*)d_in[2];   // (B,C,N) f32
    float* out = (float*)d_out;                  // (B,67,S,K) f32

    // workspace layout (16B-aligned)
    char* w = (char*)d_ws;
    const size_t cs_off    = 0;                          // 4*1001*4 = 16016
    const size_t goff_off  = 16384;                      // 4*1000*4 = 16000
    const size_t spts_off  = 32768;                      // 4*8192*16 = 512K
    const size_t featT_off = 32768 + 524288;             // 8 MB
    const size_t total_need = featT_off + (size_t)BATCH * N_PTS * CHANS * 4;

    if (ws_size >= total_need) {
        int*    cellStart = (int*)(w + cs_off);
        int*    gOff      = (int*)(w + goff_off);
        float4* sPts      = (float4*)(w + spts_off);
        float*  featT     = (float*)(w + featT_off);

        histscan_transpose<<<dim3(BATCH + BATCH * (N_PTS / 64)), dim3(256),
                             0, stream>>>(xyz, feat, cellStart, gOff, featT);
        grid_scatter<<<dim3(BATCH * N_PTS / 256), dim3(256), 0, stream>>>(
            xyz, gOff, sPts);
        bq_gather<<<dim3(BATCH * S_CTR / 4), dim3(256), 0, stream>>>(
            xyz, ctr, cellStart, sPts, featT, out);
    } else {
        int* idx_ws = (int*)w;                   // 1 MB
        bq_brute<<<dim3(BATCH * S_CTR / 4), dim3(256), 0, stream>>>(
            xyz, ctr, idx_ws);
        gather_direct<<<dim3(BATCH * S_CTR / 4), dim3(256), 0, stream>>>(
            xyz, ctr, feat, idx_ws, out);
    }
}